// Round 1
// baseline (938.968 us; speedup 1.0000x reference)
//
#include <hip/hip_runtime.h>

#define FH 128        // feature width (IN == H == 128)
#define CHUNK 1024    // scan chunk

// ---------------- CSR build ----------------

__global__ __launch_bounds__(256)
void k_init(float* deg, int* cnt, int N) {
    int i = blockIdx.x * 256 + threadIdx.x;
    if (i < N) { deg[i] = 1.0f; cnt[i] = 0; }   // deg starts at 1.0 (self-loop w=1)
}

__global__ __launch_bounds__(256)
void k_edge_hist(const int* __restrict__ dst, const float* __restrict__ w,
                 float* deg, int* cnt, int E) {
    int e = blockIdx.x * 256 + threadIdx.x;
    if (e < E) {
        int d = dst[e];
        atomicAdd(&deg[d], w[e]);
        atomicAdd(&cnt[d], 1);
    }
}

__global__ __launch_bounds__(256)
void k_dis(const float* __restrict__ deg, float* dis, float* selfn, int N) {
    int i = blockIdx.x * 256 + threadIdx.x;
    if (i < N) {
        float d = deg[i];          // >= 1 always
        float r = rsqrtf(d);
        dis[i]   = r;
        selfn[i] = r * r;          // self-loop norm = dis^2
    }
}

__global__ __launch_bounds__(256)
void k_scan_chunk(const int* __restrict__ cnt, int* __restrict__ rowptr,
                  int* __restrict__ bsum, int N) {
    __shared__ int lds[256];
    int t = threadIdx.x;
    int base = blockIdx.x * CHUNK + t * 4;
    int c0 = (base + 0 < N) ? cnt[base + 0] : 0;
    int c1 = (base + 1 < N) ? cnt[base + 1] : 0;
    int c2 = (base + 2 < N) ? cnt[base + 2] : 0;
    int c3 = (base + 3 < N) ? cnt[base + 3] : 0;
    int tsum = c0 + c1 + c2 + c3;
    int v = tsum;
    lds[t] = v;
    __syncthreads();
    #pragma unroll
    for (int off = 1; off < 256; off <<= 1) {
        int add = (t >= off) ? lds[t - off] : 0;
        __syncthreads();
        v += add;
        lds[t] = v;
        __syncthreads();
    }
    int ex = v - tsum;  // exclusive prefix of this thread's 4
    if (base + 0 < N) rowptr[base + 0] = ex; ex += c0;
    if (base + 1 < N) rowptr[base + 1] = ex; ex += c1;
    if (base + 2 < N) rowptr[base + 2] = ex; ex += c2;
    if (base + 3 < N) rowptr[base + 3] = ex;
    if (t == 255) bsum[blockIdx.x] = v;     // chunk total
}

__global__ __launch_bounds__(128)
void k_scan_blocks(const int* __restrict__ bsum, int* __restrict__ boff, int NB) {
    __shared__ int lds[128];
    int t = threadIdx.x;
    int x = (t < NB) ? bsum[t] : 0;
    int v = x;
    lds[t] = v;
    __syncthreads();
    #pragma unroll
    for (int off = 1; off < 128; off <<= 1) {
        int add = (t >= off) ? lds[t - off] : 0;
        __syncthreads();
        v += add;
        lds[t] = v;
        __syncthreads();
    }
    boff[t] = v - x;    // exclusive
}

__global__ __launch_bounds__(256)
void k_add_off(int* rowptr, int* cursor, const int* __restrict__ boff, int N, int E) {
    int i = blockIdx.x * 256 + threadIdx.x;
    if (i < N) {
        int r = rowptr[i] + boff[i >> 10];
        rowptr[i] = r;
        cursor[i] = r;
    }
    if (i == 0) rowptr[N] = E;
}

__global__ __launch_bounds__(256)
void k_fill(const int* __restrict__ src, const int* __restrict__ dst,
            const float* __restrict__ w, const float* __restrict__ dis,
            int* cursor, int* __restrict__ col, float* __restrict__ val, int E) {
    int e = blockIdx.x * 256 + threadIdx.x;
    if (e < E) {
        int s = src[e], d = dst[e];
        int p = atomicAdd(&cursor[d], 1);
        col[p] = s;
        val[p] = dis[s] * w[e] * dis[d];
    }
}

// ---------------- dense matmul: Y = act(X) @ W ----------------
// W (128x128, 64KB) resident in LDS; 32-row X tile staged transposed (16KB).
// 8 rows/wave, 2 cols/lane: per k = 2 broadcast b128 + 1 b64 + 16 FMA.

template<bool RELU>
__global__ __launch_bounds__(256, 2)
void k_mm(const float* __restrict__ X, const float* __restrict__ W,
          float* __restrict__ Y, int nrows) {
    __shared__ float Wl[FH * FH];
    __shared__ float XT[FH][32];
    {
        const float4* W4 = (const float4*)W;
        float4* Wl4 = (float4*)Wl;
        #pragma unroll
        for (int i = 0; i < 16; ++i)
            Wl4[threadIdx.x + 256 * i] = W4[threadIdx.x + 256 * i];
    }
    const int lane = threadIdx.x & 63;
    const int wave = threadIdx.x >> 6;
    const int tr = threadIdx.x >> 3;   // 0..31 : row within tile
    const int tk = threadIdx.x & 7;    // 0..7
    for (int base = blockIdx.x * 32; base < nrows; base += gridDim.x * 32) {
        __syncthreads();               // protect XT from previous iter's readers
        #pragma unroll
        for (int hh = 0; hh < 4; ++hh) {
            int kg = tk + 8 * hh;      // float4 group 0..31
            float4 v = ((const float4*)X)[(size_t)(base + tr) * 32 + kg];
            if (RELU) {
                v.x = fmaxf(v.x, 0.f); v.y = fmaxf(v.y, 0.f);
                v.z = fmaxf(v.z, 0.f); v.w = fmaxf(v.w, 0.f);
            }
            XT[kg * 4 + 0][tr] = v.x;
            XT[kg * 4 + 1][tr] = v.y;
            XT[kg * 4 + 2][tr] = v.z;
            XT[kg * 4 + 3][tr] = v.w;
        }
        __syncthreads();
        float2 acc[8];
        #pragma unroll
        for (int r = 0; r < 8; ++r) acc[r] = make_float2(0.f, 0.f);
        #pragma unroll 4
        for (int k = 0; k < FH; ++k) {
            float4 xa = *(const float4*)&XT[k][wave * 8];
            float4 xb = *(const float4*)&XT[k][wave * 8 + 4];
            float2 w2 = *(const float2*)&Wl[k * FH + lane * 2];
            acc[0].x = fmaf(xa.x, w2.x, acc[0].x); acc[0].y = fmaf(xa.x, w2.y, acc[0].y);
            acc[1].x = fmaf(xa.y, w2.x, acc[1].x); acc[1].y = fmaf(xa.y, w2.y, acc[1].y);
            acc[2].x = fmaf(xa.z, w2.x, acc[2].x); acc[2].y = fmaf(xa.z, w2.y, acc[2].y);
            acc[3].x = fmaf(xa.w, w2.x, acc[3].x); acc[3].y = fmaf(xa.w, w2.y, acc[3].y);
            acc[4].x = fmaf(xb.x, w2.x, acc[4].x); acc[4].y = fmaf(xb.x, w2.y, acc[4].y);
            acc[5].x = fmaf(xb.y, w2.x, acc[5].x); acc[5].y = fmaf(xb.y, w2.y, acc[5].y);
            acc[6].x = fmaf(xb.z, w2.x, acc[6].x); acc[6].y = fmaf(xb.z, w2.y, acc[6].y);
            acc[7].x = fmaf(xb.w, w2.x, acc[7].x); acc[7].y = fmaf(xb.w, w2.y, acc[7].y);
        }
        #pragma unroll
        for (int r = 0; r < 8; ++r)
            ((float2*)Y)[(size_t)(base + wave * 8 + r) * 64 + lane] = acc[r];
    }
}

// ---------------- aggregation: out[i] = selfn[i]*tmp[i] + sum_e val*tmp[col] + b (+ ori) ----------------
// one wave per node; lane holds float2 of the 128-wide feature row.

template<bool RESID>
__global__ __launch_bounds__(256)
void k_agg(const float* __restrict__ tmp, const int* __restrict__ rowptr,
           const int* __restrict__ col, const float* __restrict__ val,
           const float* __restrict__ selfn, const float* __restrict__ bias,
           const float* __restrict__ ori, float* __restrict__ out, int N) {
    int wave = threadIdx.x >> 6, lane = threadIdx.x & 63;
    int row = blockIdx.x * 4 + wave;
    if (row >= N) return;
    const float2* t2 = (const float2*)tmp;
    int start = rowptr[row], end = rowptr[row + 1];
    float2 b2 = ((const float2*)bias)[lane];
    float sn = selfn[row];
    float2 self = t2[(size_t)row * 64 + lane];
    float2 acc;
    acc.x = fmaf(sn, self.x, b2.x);
    acc.y = fmaf(sn, self.y, b2.y);
    int e = start;
    for (; e + 2 <= end; e += 2) {
        int c0 = col[e], c1 = col[e + 1];
        float v0 = val[e], v1 = val[e + 1];
        float2 t0 = t2[(size_t)c0 * 64 + lane];
        float2 t1 = t2[(size_t)c1 * 64 + lane];
        acc.x = fmaf(v0, t0.x, acc.x); acc.y = fmaf(v0, t0.y, acc.y);
        acc.x = fmaf(v1, t1.x, acc.x); acc.y = fmaf(v1, t1.y, acc.y);
    }
    if (e < end) {
        int c0 = col[e];
        float v0 = val[e];
        float2 t0 = t2[(size_t)c0 * 64 + lane];
        acc.x = fmaf(v0, t0.x, acc.x); acc.y = fmaf(v0, t0.y, acc.y);
    }
    if (RESID) {
        float2 o = ((const float2*)ori)[(size_t)row * 64 + lane];
        acc.x += o.x; acc.y += o.y;
    }
    ((float2*)out)[(size_t)row * 64 + lane] = acc;
}

// ---------------- launch ----------------

extern "C" void kernel_launch(void* const* d_in, const int* in_sizes, int n_in,
                              void* d_out, int out_size, void* d_ws, size_t ws_size,
                              hipStream_t stream) {
    const int*   edge_index = (const int*)d_in[0];
    const float* in_feat    = (const float*)d_in[1];
    const float* ew         = (const float*)d_in[2];
    const float* W1         = (const float*)d_in[3];
    const float* b1         = (const float*)d_in[4];
    const float* W2         = (const float*)d_in[5];
    const float* b2         = (const float*)d_in[6];
    const int E = in_sizes[0] / 2;
    const int N = in_sizes[1] / FH;
    const int* src = edge_index;
    const int* dst = edge_index + E;

    char* ws = (char*)d_ws;
    size_t o = 0;
    auto alloc = [&](size_t bytes) -> void* {
        void* p = ws + o;
        o += (bytes + 255) & ~(size_t)255;
        return p;
    };
    float* tmp    = (float*)alloc((size_t)N * FH * 4);
    float* h1     = (float*)alloc((size_t)N * FH * 4);
    int*   col    = (int*)  alloc((size_t)E * 4);
    float* val    = (float*)alloc((size_t)E * 4);
    float* deg    = (float*)alloc((size_t)N * 4);
    float* dis    = (float*)alloc((size_t)N * 4);
    float* selfn  = (float*)alloc((size_t)N * 4);
    int*   cnt    = (int*)  alloc((size_t)N * 4);
    int*   rowptr = (int*)  alloc((size_t)(N + 1) * 4);
    int*   cursor = (int*)  alloc((size_t)N * 4);
    int*   bsum   = (int*)  alloc(512);
    int*   boff   = (int*)  alloc(512);

    int gN = (N + 255) / 256;
    int gE = (E + 255) / 256;
    int NB = (N + CHUNK - 1) / CHUNK;    // 98 <= 128

    k_init<<<gN, 256, 0, stream>>>(deg, cnt, N);
    k_edge_hist<<<gE, 256, 0, stream>>>(dst, ew, deg, cnt, E);
    k_dis<<<gN, 256, 0, stream>>>(deg, dis, selfn, N);
    k_scan_chunk<<<NB, 256, 0, stream>>>(cnt, rowptr, bsum, N);
    k_scan_blocks<<<1, 128, 0, stream>>>(bsum, boff, NB);
    k_add_off<<<gN, 256, 0, stream>>>(rowptr, cursor, boff, N, E);
    k_fill<<<gE, 256, 0, stream>>>(src, dst, ew, dis, cursor, col, val, E);

    float* out = (float*)d_out;
    int gAgg = (N + 3) / 4;

    // layer 1: h1 = A @ (x @ W1) + b1
    k_mm<false><<<512, 256, 0, stream>>>(in_feat, W1, tmp, N);
    k_agg<false><<<gAgg, 256, 0, stream>>>(tmp, rowptr, col, val, selfn, b1, nullptr, h1, N);
    // layer 2: out = A @ (relu(h1) @ W2) + b2 + h1
    k_mm<true><<<512, 256, 0, stream>>>(h1, W2, tmp, N);
    k_agg<true><<<gAgg, 256, 0, stream>>>(tmp, rowptr, col, val, selfn, b2, h1, out, N);
    // layer 3: out = A @ (relu(out) @ W2) + b2 + h1
    k_mm<true><<<512, 256, 0, stream>>>(out, W2, tmp, N);
    k_agg<true><<<gAgg, 256, 0, stream>>>(tmp, rowptr, col, val, selfn, b2, h1, out, N);
}

// Round 6
// 784.546 us; speedup vs baseline: 1.1968x; 1.1968x over previous
//
#include <hip/hip_runtime.h>

#define FH 128        // feature width (IN == H == 128)
#define CHUNK 1024    // scan chunk
#define RSHIFT 42     // rank field shift in packed histogram
#define WSCALE 4294967296.0f   // 2^32 fixed-point scale for edge weights

typedef unsigned long long u64;

// ---------------- CSR build ----------------

__global__ __launch_bounds__(256)
void k_zero(u64* hist, int N) {
    int i = blockIdx.x * 256 + threadIdx.x;
    if (i < N) hist[i] = 0ull;
}

// one packed u64 atomic per edge: low 42 bits = sum(w * 2^32), high bits = count.
// returned old count field = this edge's rank within its dst row.
__global__ __launch_bounds__(256)
void k_hist(const int* __restrict__ dst, const float* __restrict__ w,
            u64* hist, unsigned int* __restrict__ rank, int E) {
    int e = blockIdx.x * 256 + threadIdx.x;
    if (e < E) {
        int d = dst[e];
        u64 inc = ((u64)1 << RSHIFT) | (u64)(w[e] * WSCALE);
        u64 old = atomicAdd(&hist[d], inc);
        rank[e] = (unsigned int)(old >> RSHIFT);
    }
}

__global__ __launch_bounds__(256)
void k_dis(const u64* __restrict__ hist, float* dis, float* selfn, int N) {
    int i = blockIdx.x * 256 + threadIdx.x;
    if (i < N) {
        u64 p = hist[i];
        float deg = 1.0f + (float)(p & (((u64)1 << RSHIFT) - 1)) * (1.0f / WSCALE);
        float r = rsqrtf(deg);
        dis[i]   = r;
        selfn[i] = r * r;          // self-loop norm = dis^2
    }
}

__global__ __launch_bounds__(256)
void k_scan_chunk(const u64* __restrict__ hist, int* __restrict__ rowptr,
                  int* __restrict__ bsum, int N) {
    __shared__ int lds[256];
    int t = threadIdx.x;
    int base = blockIdx.x * CHUNK + t * 4;
    int c0 = (base + 0 < N) ? (int)(hist[base + 0] >> RSHIFT) : 0;
    int c1 = (base + 1 < N) ? (int)(hist[base + 1] >> RSHIFT) : 0;
    int c2 = (base + 2 < N) ? (int)(hist[base + 2] >> RSHIFT) : 0;
    int c3 = (base + 3 < N) ? (int)(hist[base + 3] >> RSHIFT) : 0;
    int tsum = c0 + c1 + c2 + c3;
    int v = tsum;
    lds[t] = v;
    __syncthreads();
    #pragma unroll
    for (int off = 1; off < 256; off <<= 1) {
        int add = (t >= off) ? lds[t - off] : 0;
        __syncthreads();
        v += add;
        lds[t] = v;
        __syncthreads();
    }
    int ex = v - tsum;  // exclusive prefix of this thread's 4
    if (base + 0 < N) rowptr[base + 0] = ex; ex += c0;
    if (base + 1 < N) rowptr[base + 1] = ex; ex += c1;
    if (base + 2 < N) rowptr[base + 2] = ex; ex += c2;
    if (base + 3 < N) rowptr[base + 3] = ex;
    if (t == 255) bsum[blockIdx.x] = v;     // chunk total
}

__global__ __launch_bounds__(128)
void k_scan_blocks(const int* __restrict__ bsum, int* __restrict__ boff, int NB) {
    __shared__ int lds[128];
    int t = threadIdx.x;
    int x = (t < NB) ? bsum[t] : 0;
    int v = x;
    lds[t] = v;
    __syncthreads();
    #pragma unroll
    for (int off = 1; off < 128; off <<= 1) {
        int add = (t >= off) ? lds[t - off] : 0;
        __syncthreads();
        v += add;
        lds[t] = v;
        __syncthreads();
    }
    boff[t] = v - x;    // exclusive
}

__global__ __launch_bounds__(256)
void k_add_off(int* rowptr, const int* __restrict__ boff, int N, int E) {
    int i = blockIdx.x * 256 + threadIdx.x;
    if (i < N) rowptr[i] += boff[i >> 10];
    if (i == 0) rowptr[N] = E;
}

// no atomic: position = rowptr[dst] + rank (rank captured in k_hist).
// col+val fused into one 8B write.
__global__ __launch_bounds__(256)
void k_fill(const int* __restrict__ src, const int* __restrict__ dst,
            const float* __restrict__ w, const unsigned int* __restrict__ rank,
            const float* __restrict__ dis, const int* __restrict__ rowptr,
            int2* __restrict__ pairs, int E) {
    int e = blockIdx.x * 256 + threadIdx.x;
    if (e < E) {
        int s = src[e], d = dst[e];
        int p = rowptr[d] + (int)rank[e];
        float v = dis[s] * w[e] * dis[d];
        pairs[p] = make_int2(s, __float_as_int(v));
    }
}

// ---------------- dense matmul: Y = act(X) @ W ----------------
// W (128x128, 64KB) resident in LDS; 32-row X tile staged transposed (16KB).

template<bool RELU>
__global__ __launch_bounds__(256, 2)
void k_mm(const float* __restrict__ X, const float* __restrict__ W,
          float* __restrict__ Y, int nrows) {
    __shared__ float Wl[FH * FH];
    __shared__ float XT[FH][32];
    {
        const float4* W4 = (const float4*)W;
        float4* Wl4 = (float4*)Wl;
        #pragma unroll
        for (int i = 0; i < 16; ++i)
            Wl4[threadIdx.x + 256 * i] = W4[threadIdx.x + 256 * i];
    }
    const int lane = threadIdx.x & 63;
    const int wave = threadIdx.x >> 6;
    const int tr = threadIdx.x >> 3;   // 0..31 : row within tile
    const int tk = threadIdx.x & 7;    // 0..7
    for (int base = blockIdx.x * 32; base < nrows; base += gridDim.x * 32) {
        __syncthreads();               // protect XT from previous iter's readers
        #pragma unroll
        for (int hh = 0; hh < 4; ++hh) {
            int kg = tk + 8 * hh;      // float4 group 0..31
            float4 v = ((const float4*)X)[(size_t)(base + tr) * 32 + kg];
            if (RELU) {
                v.x = fmaxf(v.x, 0.f); v.y = fmaxf(v.y, 0.f);
                v.z = fmaxf(v.z, 0.f); v.w = fmaxf(v.w, 0.f);
            }
            XT[kg * 4 + 0][tr] = v.x;
            XT[kg * 4 + 1][tr] = v.y;
            XT[kg * 4 + 2][tr] = v.z;
            XT[kg * 4 + 3][tr] = v.w;
        }
        __syncthreads();
        float2 acc[8];
        #pragma unroll
        for (int r = 0; r < 8; ++r) acc[r] = make_float2(0.f, 0.f);
        #pragma unroll 4
        for (int k = 0; k < FH; ++k) {
            float4 xa = *(const float4*)&XT[k][wave * 8];
            float4 xb = *(const float4*)&XT[k][wave * 8 + 4];
            float2 w2 = *(const float2*)&Wl[k * FH + lane * 2];
            acc[0].x = fmaf(xa.x, w2.x, acc[0].x); acc[0].y = fmaf(xa.x, w2.y, acc[0].y);
            acc[1].x = fmaf(xa.y, w2.x, acc[1].x); acc[1].y = fmaf(xa.y, w2.y, acc[1].y);
            acc[2].x = fmaf(xa.z, w2.x, acc[2].x); acc[2].y = fmaf(xa.z, w2.y, acc[2].y);
            acc[3].x = fmaf(xa.w, w2.x, acc[3].x); acc[3].y = fmaf(xa.w, w2.y, acc[3].y);
            acc[4].x = fmaf(xb.x, w2.x, acc[4].x); acc[4].y = fmaf(xb.x, w2.y, acc[4].y);
            acc[5].x = fmaf(xb.y, w2.x, acc[5].x); acc[5].y = fmaf(xb.y, w2.y, acc[5].y);
            acc[6].x = fmaf(xb.z, w2.x, acc[6].x); acc[6].y = fmaf(xb.z, w2.y, acc[6].y);
            acc[7].x = fmaf(xb.w, w2.x, acc[7].x); acc[7].y = fmaf(xb.w, w2.y, acc[7].y);
        }
        #pragma unroll
        for (int r = 0; r < 8; ++r)
            ((float2*)Y)[(size_t)(base + wave * 8 + r) * 64 + lane] = acc[r];
    }
}

// ---------------- aggregation ----------------
// out[i] = selfn[i]*tmp[i] + sum_e val*tmp[col] + b (+ ori)
// one wave per node; lane holds float2 of the 128-wide row. 4x unrolled gathers.

template<bool RESID>
__global__ __launch_bounds__(256)
void k_agg(const float* __restrict__ tmp, const int* __restrict__ rowptr,
           const int2* __restrict__ pairs, const float* __restrict__ selfn,
           const float* __restrict__ bias, const float* __restrict__ ori,
           float* __restrict__ out, int N) {
    int wave = threadIdx.x >> 6, lane = threadIdx.x & 63;
    int row = blockIdx.x * 4 + wave;
    if (row >= N) return;
    const float2* t2 = (const float2*)tmp;
    int start = rowptr[row], end = rowptr[row + 1];
    float2 b2 = ((const float2*)bias)[lane];
    float sn = selfn[row];
    float2 self = t2[(size_t)row * 64 + lane];
    float ax = fmaf(sn, self.x, b2.x);
    float ay = fmaf(sn, self.y, b2.y);
    int e = start;
    for (; e + 4 <= end; e += 4) {
        int2 q0 = pairs[e], q1 = pairs[e + 1], q2 = pairs[e + 2], q3 = pairs[e + 3];
        float2 t0 = t2[(size_t)q0.x * 64 + lane];
        float2 t1 = t2[(size_t)q1.x * 64 + lane];
        float2 t2v = t2[(size_t)q2.x * 64 + lane];
        float2 t3 = t2[(size_t)q3.x * 64 + lane];
        float v0 = __int_as_float(q0.y), v1 = __int_as_float(q1.y);
        float v2 = __int_as_float(q2.y), v3 = __int_as_float(q3.y);
        ax = fmaf(v0, t0.x, ax); ay = fmaf(v0, t0.y, ay);
        ax = fmaf(v1, t1.x, ax); ay = fmaf(v1, t1.y, ay);
        ax = fmaf(v2, t2v.x, ax); ay = fmaf(v2, t2v.y, ay);
        ax = fmaf(v3, t3.x, ax); ay = fmaf(v3, t3.y, ay);
    }
    for (; e < end; ++e) {
        int2 q0 = pairs[e];
        float2 t0 = t2[(size_t)q0.x * 64 + lane];
        float v0 = __int_as_float(q0.y);
        ax = fmaf(v0, t0.x, ax); ay = fmaf(v0, t0.y, ay);
    }
    if (RESID) {
        float2 o = ((const float2*)ori)[(size_t)row * 64 + lane];
        ax += o.x; ay += o.y;
    }
    ((float2*)out)[(size_t)row * 64 + lane] = make_float2(ax, ay);
}

// ---------------- launch ----------------

extern "C" void kernel_launch(void* const* d_in, const int* in_sizes, int n_in,
                              void* d_out, int out_size, void* d_ws, size_t ws_size,
                              hipStream_t stream) {
    const int*   edge_index = (const int*)d_in[0];
    const float* in_feat    = (const float*)d_in[1];
    const float* ew         = (const float*)d_in[2];
    const float* W1         = (const float*)d_in[3];
    const float* b1         = (const float*)d_in[4];
    const float* W2         = (const float*)d_in[5];
    const float* b2         = (const float*)d_in[6];
    const int E = in_sizes[0] / 2;
    const int N = in_sizes[1] / FH;
    const int* src = edge_index;
    const int* dst = edge_index + E;

    char* ws = (char*)d_ws;
    size_t o = 0;
    auto alloc = [&](size_t bytes) -> void* {
        void* p = ws + o;
        o += (bytes + 255) & ~(size_t)255;
        return p;
    };
    float*        tmp    = (float*)alloc((size_t)N * FH * 4);
    float*        h1     = (float*)alloc((size_t)N * FH * 4);
    int2*         pairs  = (int2*) alloc((size_t)E * 8);
    u64*          hist   = (u64*)  alloc((size_t)N * 8);
    unsigned int* rank   = (unsigned int*)alloc((size_t)E * 4);
    float*        dis    = (float*)alloc((size_t)N * 4);
    float*        selfn  = (float*)alloc((size_t)N * 4);
    int*          rowptr = (int*)  alloc((size_t)(N + 1) * 4);
    int*          bsum   = (int*)  alloc(512);
    int*          boff   = (int*)  alloc(512);

    int gN = (N + 255) / 256;
    int gE = (E + 255) / 256;
    int NB = (N + CHUNK - 1) / CHUNK;    // 98 <= 128

    k_zero<<<gN, 256, 0, stream>>>(hist, N);
    k_hist<<<gE, 256, 0, stream>>>(dst, ew, hist, rank, E);
    k_dis<<<gN, 256, 0, stream>>>(hist, dis, selfn, N);
    k_scan_chunk<<<NB, 256, 0, stream>>>(hist, rowptr, bsum, N);
    k_scan_blocks<<<1, 128, 0, stream>>>(bsum, boff, NB);
    k_add_off<<<gN, 256, 0, stream>>>(rowptr, boff, N, E);
    k_fill<<<gE, 256, 0, stream>>>(src, dst, ew, rank, dis, rowptr, pairs, E);

    float* out = (float*)d_out;
    int gAgg = (N + 3) / 4;

    // layer 1: h1 = A @ (x @ W1) + b1
    k_mm<false><<<512, 256, 0, stream>>>(in_feat, W1, tmp, N);
    k_agg<false><<<gAgg, 256, 0, stream>>>(tmp, rowptr, pairs, selfn, b1, nullptr, h1, N);
    // layer 2: out = A @ (relu(h1) @ W2) + b2 + h1
    k_mm<true><<<512, 256, 0, stream>>>(h1, W2, tmp, N);
    k_agg<true><<<gAgg, 256, 0, stream>>>(tmp, rowptr, pairs, selfn, b2, h1, out, N);
    // layer 3: out = A @ (relu(out) @ W2) + b2 + h1
    k_mm<true><<<512, 256, 0, stream>>>(out, W2, tmp, N);
    k_agg<true><<<gAgg, 256, 0, stream>>>(tmp, rowptr, pairs, selfn, b2, h1, out, N);
}